// Round 8
// baseline (827.605 us; speedup 1.0000x reference)
//
#include <hip/hip_runtime.h>

#define BN_EPS 1e-5f

typedef __attribute__((ext_vector_type(8))) short bf16x8;
typedef __attribute__((ext_vector_type(4))) float f32x4;

union VU {
    uint4 u;
    bf16x8 b;
};

// ---------------- CSR build ----------------

__global__ __launch_bounds__(256) void count_k(const int* __restrict__ dst, int E, int* __restrict__ cnt) {
    int i = blockIdx.x * 256 + threadIdx.x;
    if (i < E) atomicAdd(&cnt[dst[i]], 1);
}

__global__ __launch_bounds__(1024) void scan1_k(const int* __restrict__ cnt, int n, int* __restrict__ bsum) {
    __shared__ int sh[1024];
    int i = blockIdx.x * 1024 + threadIdx.x;
    sh[threadIdx.x] = (i < n) ? cnt[i] : 0;
    __syncthreads();
    for (int s = 512; s > 0; s >>= 1) {
        if (threadIdx.x < (unsigned)s) sh[threadIdx.x] += sh[threadIdx.x + s];
        __syncthreads();
    }
    if (threadIdx.x == 0) bsum[blockIdx.x] = sh[0];
}

__global__ void scan2_k(int* bsum, int nb, int* rowptr, int n, int E) {
    if (threadIdx.x == 0 && blockIdx.x == 0) {
        int run = 0;
        for (int i = 0; i < nb; ++i) { int v = bsum[i]; bsum[i] = run; run += v; }
        rowptr[n] = E;
    }
}

__global__ __launch_bounds__(1024) void scan3_k(const int* __restrict__ cnt, int n, const int* __restrict__ boff,
                                                int* __restrict__ rowptr, int* __restrict__ nxt) {
    __shared__ int sh[1024];
    int i = blockIdx.x * 1024 + threadIdx.x;
    int v = (i < n) ? cnt[i] : 0;
    sh[threadIdx.x] = v;
    __syncthreads();
    for (int s = 1; s < 1024; s <<= 1) {
        int t = (threadIdx.x >= (unsigned)s) ? sh[threadIdx.x - s] : 0;
        __syncthreads();
        sh[threadIdx.x] += t;
        __syncthreads();
    }
    if (i < n) {
        int ex = boff[blockIdx.x] + sh[threadIdx.x] - v;
        rowptr[i] = ex;
        nxt[i] = ex;
    }
}

__global__ __launch_bounds__(256) void scatter_k(const int* __restrict__ src, const int* __restrict__ dst, int E,
                                                 int* __restrict__ nxt, int* __restrict__ ssrc) {
    int i = blockIdx.x * 256 + threadIdx.x;
    if (i < E) {
        int d = dst[i];
        int p = atomicAdd(&nxt[d], 1);
        ssrc[p] = src[i];
    }
}

// ---------------- helpers ----------------

static __device__ __forceinline__ unsigned short f2bf(float f) {
    unsigned u = __float_as_uint(f);
    unsigned r = (u + 0x7FFFu + ((u >> 16) & 1u)) >> 16;  // RNE
    return (unsigned short)r;
}
static __device__ __forceinline__ float bf_lo(unsigned u) { return __uint_as_float(u << 16); }
static __device__ __forceinline__ float bf_hi(unsigned u) { return __uint_as_float(u & 0xFFFF0000u); }

// ---------------- prep: pack W (3 layers f32 128x128) into bf16 MFMA fragments ----------------

__global__ __launch_bounds__(256) void prepw_k(const float* __restrict__ Ws, uint4* __restrict__ Wp) {
    int id = blockIdx.x * 256 + threadIdx.x;
    if (id >= 3 * 4 * 8 * 64) return;
    int lane = id & 63;
    int nt = (id >> 6) & 7;
    int kt = (id >> 9) & 3;
    int L = id >> 11;
    int quad = lane >> 4, l16 = lane & 15;
    const float* wsrc = Ws + L * 16384 + (kt * 32 + quad * 8) * 128 + nt * 16 + l16;
    unsigned short s[8];
#pragma unroll
    for (int j = 0; j < 8; ++j) s[j] = f2bf(wsrc[j * 128]);
    uint4 pk;
    pk.x = (unsigned)s[0] | ((unsigned)s[1] << 16);
    pk.y = (unsigned)s[2] | ((unsigned)s[3] << 16);
    pk.z = (unsigned)s[4] | ((unsigned)s[5] << 16);
    pk.w = (unsigned)s[6] | ((unsigned)s[7] << 16);
    Wp[id] = pk;
}

// ---------------- MFMA GEMM: H(bf16, SLICE-MAJOR) = f(X) @ Wp ----------------
// Slice-major: H is 8 arrays of N x 16 feats (32B rows); slice s at H + s*N*16, holds feats [16s,16s+16).
// MODE 0: X = f32 row-major (cvt fused).  MODE 1: X = bf16 slice-major, f = BN+ReLU (fused).
// Wave-per-16-row-tile, grid-strided; W resident in 128 VGPRs; no LDS, no barriers.

template <int MODE>
__global__ __launch_bounds__(256) void mgemm_k(const float* __restrict__ Xf, const unsigned short* __restrict__ Xb,
                                               const uint4* __restrict__ Wp, unsigned short* __restrict__ H,
                                               const float* __restrict__ ss, int n) {
    int lane = threadIdx.x & 63;
    int quad = lane >> 4, l16 = lane & 15;
    int wid = (blockIdx.x * 256 + threadIdx.x) >> 6;
    int nw = (gridDim.x * 256) >> 6;
    int ntiles = (n + 15) >> 4;  // n = 100000 -> exact

    VU b[4][8];
#pragma unroll
    for (int kt = 0; kt < 4; ++kt)
#pragma unroll
        for (int nt = 0; nt < 8; ++nt) b[kt][nt].u = Wp[(kt * 8 + nt) * 64 + lane];

    auto loadA = [&](int tile, VU* a) {
        int row = tile * 16 + l16;
#pragma unroll
        for (int kt = 0; kt < 4; ++kt) {
            float f[8];
            if (MODE == 0) {
                const float* xr = Xf + (size_t)row * 128 + kt * 32 + quad * 8;
                float4 u0 = *(const float4*)(xr);
                float4 u1 = *(const float4*)(xr + 4);
                f[0] = u0.x; f[1] = u0.y; f[2] = u0.z; f[3] = u0.w;
                f[4] = u1.x; f[5] = u1.y; f[6] = u1.z; f[7] = u1.w;
            } else {
                int sl = kt * 2 + (quad >> 1);  // slice containing k-range
                uint4 u = *(const uint4*)(Xb + ((size_t)sl * n + row) * 16 + (quad & 1) * 8);
                f[0] = bf_lo(u.x); f[1] = bf_hi(u.x); f[2] = bf_lo(u.y); f[3] = bf_hi(u.y);
                f[4] = bf_lo(u.z); f[5] = bf_hi(u.z); f[6] = bf_lo(u.w); f[7] = bf_hi(u.w);
                const float4* scp = (const float4*)(ss + kt * 32 + quad * 8);
                const float4* shp = (const float4*)(ss + 128 + kt * 32 + quad * 8);
                float4 c0 = scp[0], c1 = scp[1], d0 = shp[0], d1 = shp[1];
                f[0] = fmaxf(fmaf(f[0], c0.x, d0.x), 0.f);
                f[1] = fmaxf(fmaf(f[1], c0.y, d0.y), 0.f);
                f[2] = fmaxf(fmaf(f[2], c0.z, d0.z), 0.f);
                f[3] = fmaxf(fmaf(f[3], c0.w, d0.w), 0.f);
                f[4] = fmaxf(fmaf(f[4], c1.x, d1.x), 0.f);
                f[5] = fmaxf(fmaf(f[5], c1.y, d1.y), 0.f);
                f[6] = fmaxf(fmaf(f[6], c1.z, d1.z), 0.f);
                f[7] = fmaxf(fmaf(f[7], c1.w, d1.w), 0.f);
            }
            uint4 pk;
            pk.x = (unsigned)f2bf(f[0]) | ((unsigned)f2bf(f[1]) << 16);
            pk.y = (unsigned)f2bf(f[2]) | ((unsigned)f2bf(f[3]) << 16);
            pk.z = (unsigned)f2bf(f[4]) | ((unsigned)f2bf(f[5]) << 16);
            pk.w = (unsigned)f2bf(f[6]) | ((unsigned)f2bf(f[7]) << 16);
            a[kt].u = pk;
        }
    };

    int t = wid;
    VU a[4];
    if (t < ntiles) loadA(t, a);

    while (t < ntiles) {
        int tn = t + nw;
        VU an[4];
        if (tn < ntiles) loadA(tn, an);

        f32x4 acc[8];
#pragma unroll
        for (int nt = 0; nt < 8; ++nt) acc[nt] = (f32x4){0.f, 0.f, 0.f, 0.f};
#pragma unroll
        for (int kt = 0; kt < 4; ++kt)
#pragma unroll
            for (int nt = 0; nt < 8; ++nt)
                acc[nt] = __builtin_amdgcn_mfma_f32_16x16x32_bf16(b[kt][nt].b, a[kt].b, acc[nt], 0, 0, 0);

        int row = t * 16 + l16;
#pragma unroll
        for (int nt = 0; nt < 8; ++nt) {
            uint2 pk;
            pk.x = (unsigned)f2bf(acc[nt][0]) | ((unsigned)f2bf(acc[nt][1]) << 16);
            pk.y = (unsigned)f2bf(acc[nt][2]) | ((unsigned)f2bf(acc[nt][3]) << 16);
            *(uint2*)(H + ((size_t)nt * n + row) * 16 + quad * 4) = pk;
        }

#pragma unroll
        for (int kt = 0; kt < 4; ++kt) a[kt] = an[kt];
        t = tn;
    }
}

// ---------------- Sliced aggregation: out[n] = sum_{e in CSR[n]} H[src[e]], one 16-feat slice per block ----------------
// slice = blockIdx & 7 -> pins each slice to one XCD (round-robin dispatch) -> 3.2 MB slice is L2-resident.
// Wave: 8 edges x 8 lanes, lane reads 4 B (2 bf16 feats). Branch-free clamp+scale tails.
// MODE 0: write bf16 slice-major + BN stats.  MODE 1: write f32 row-major (log_softmax done by lsm_k).

template <int MODE>
__global__ __launch_bounds__(256) void aggs_k(const unsigned short* __restrict__ H, const int* __restrict__ rowptr,
                                              const int* __restrict__ ssrc, unsigned* __restrict__ outb,
                                              float* __restrict__ outf, float* __restrict__ stats, int n) {
    __shared__ float sred[4][4][8];
    int slice = blockIdx.x & 7;
    int bg = blockIdx.x >> 3;
    int lane = threadIdx.x & 63;
    int wv = threadIdx.x >> 6;
    int eg = lane >> 3;  // edge within group of 8
    int f = lane & 7;    // feature pair: feats 2f, 2f+1 of this slice
    int wid = bg * 4 + wv;
    int nw = (gridDim.x >> 3) * 4;  // waves per slice
    const unsigned short* hs = H + (size_t)slice * n * 16 + f * 2;
    float s0 = 0, s1 = 0, q0 = 0, q1 = 0;

    for (int node = wid; node < n; node += nw) {
        int beg = rowptr[node], end = rowptr[node + 1];
        float ax = 0.f, ay = 0.f;
        int e = beg;
        for (; e + 16 <= end; e += 16) {
            int i0 = ssrc[e + eg];
            int i1 = ssrc[e + 8 + eg];
            unsigned v0 = *(const unsigned*)(hs + (size_t)i0 * 16);
            unsigned v1 = *(const unsigned*)(hs + (size_t)i1 * 16);
            ax += bf_lo(v0) + bf_lo(v1);
            ay += bf_hi(v0) + bf_hi(v1);
        }
        for (; e < end; e += 8) {
            int j = e + eg;
            int cj = (j < end) ? j : (end - 1);
            unsigned v = *(const unsigned*)(hs + (size_t)ssrc[cj] * 16);
            float sc = (j < end) ? 1.f : 0.f;
            ax += sc * bf_lo(v);
            ay += sc * bf_hi(v);
        }
        // reduce across the 8 edge-groups (lane bits 3,4,5)
        ax += __shfl_xor(ax, 8);  ay += __shfl_xor(ay, 8);
        ax += __shfl_xor(ax, 16); ay += __shfl_xor(ay, 16);
        ax += __shfl_xor(ax, 32); ay += __shfl_xor(ay, 32);

        if (MODE == 0) {
            if (eg == 0) outb[((size_t)slice * n + node) * 8 + f] = (unsigned)f2bf(ax) | ((unsigned)f2bf(ay) << 16);
            s0 += ax; q0 += ax * ax;
            s1 += ay; q1 += ay * ay;
        } else {
            if (eg == 0) *(float2*)(outf + (size_t)node * 128 + slice * 16 + f * 2) = make_float2(ax, ay);
        }
    }

    if (MODE == 0) {
        if (eg == 0) {
            sred[wv][0][f] = s0;
            sred[wv][1][f] = s1;
            sred[wv][2][f] = q0;
            sred[wv][3][f] = q1;
        }
        __syncthreads();
        if (wv == 0 && eg == 0) {
            float t0 = (sred[0][0][f] + sred[1][0][f]) + (sred[2][0][f] + sred[3][0][f]);
            float t1 = (sred[0][1][f] + sred[1][1][f]) + (sred[2][1][f] + sred[3][1][f]);
            float t2 = (sred[0][2][f] + sred[1][2][f]) + (sred[2][2][f] + sred[3][2][f]);
            float t3 = (sred[0][3][f] + sred[1][3][f]) + (sred[2][3][f] + sred[3][3][f]);
            atomicAdd(&stats[slice * 16 + 2 * f], t0);
            atomicAdd(&stats[slice * 16 + 2 * f + 1], t1);
            atomicAdd(&stats[128 + slice * 16 + 2 * f], t2);
            atomicAdd(&stats[128 + slice * 16 + 2 * f + 1], t3);
        }
    }
}

// ---------------- log_softmax in-place over out [n][128] ----------------

__global__ __launch_bounds__(256) void lsm_k(float* __restrict__ out, int n) {
    int lane = threadIdx.x & 63;
    int wid = (blockIdx.x * 256 + threadIdx.x) >> 6;
    int nw = (gridDim.x * 256) >> 6;
    for (int node = wid; node < n; node += nw) {
        float2 v = *(float2*)(out + (size_t)node * 128 + 2 * lane);
        float m = fmaxf(v.x, v.y);
#pragma unroll
        for (int off = 32; off > 0; off >>= 1) m = fmaxf(m, __shfl_xor(m, off));
        float ex = expf(v.x - m) + expf(v.y - m);
#pragma unroll
        for (int off = 32; off > 0; off >>= 1) ex += __shfl_xor(ex, off);
        float lse = m + logf(ex);
        *(float2*)(out + (size_t)node * 128 + 2 * lane) = make_float2(v.x - lse, v.y - lse);
    }
}

// ---------------- BN finalize ----------------

__global__ void bnfin_k(const float* __restrict__ stats, const float* __restrict__ gamma,
                        const float* __restrict__ beta, float* __restrict__ ss, int n) {
    int f = threadIdx.x;
    if (f < 128) {
        float mu = stats[f] / n;
        float var = stats[128 + f] / n - mu * mu;
        float rs = rsqrtf(fmaxf(var, 0.f) + BN_EPS);
        float sc = gamma[f] * rs;
        ss[f] = sc;
        ss[128 + f] = beta[f] - mu * sc;
    }
}

// ---------------- driver ----------------

extern "C" void kernel_launch(void* const* d_in, const int* in_sizes, int n_in,
                              void* d_out, int out_size, void* d_ws, size_t ws_size,
                              hipStream_t stream) {
    const float* x = (const float*)d_in[0];
    const int* ei = (const int*)d_in[1];
    const float* Ws = (const float*)d_in[2];
    const float* gammas = (const float*)d_in[3];
    const float* betas = (const float*)d_in[4];
    int N = in_sizes[0] / 128;
    int E = in_sizes[1] / 2;
    const int* src = ei;
    const int* dst = ei + E;
    float* out = (float*)d_out;

    char* w = (char*)d_ws;
    size_t o = 0;
    auto alloc = [&](size_t bytes) { char* p = w + o; o += (bytes + 511) & ~511ull; return p; };
    unsigned short* h = (unsigned short*)alloc((size_t)N * 128 * 2);   // bf16 slice-major GEMM out / agg in
    unsigned short* h2 = (unsigned short*)alloc((size_t)N * 128 * 2);  // bf16 slice-major agg out / GEMM in
    int* cnt = (int*)alloc((size_t)N * 4);
    int* rowptr = (int*)alloc(((size_t)N + 1) * 4);
    int* nxt = (int*)alloc((size_t)N * 4);
    int* bsum = (int*)alloc(4096);
    int* ssrc = (int*)alloc((size_t)E * 4);
    uint4* Wp = (uint4*)alloc(3 * 2048 * 16);
    float* stats = (float*)alloc(512 * 4);
    float* ss = (float*)alloc(512 * 4);

    hipMemsetAsync(cnt, 0, (size_t)N * 4, stream);
    hipMemsetAsync(stats, 0, 512 * 4, stream);

    int ebl = (E + 255) / 256;
    int nb = (N + 1023) / 1024;
    prepw_k<<<24, 256, 0, stream>>>(Ws, Wp);
    count_k<<<ebl, 256, 0, stream>>>(dst, E, cnt);
    scan1_k<<<nb, 1024, 0, stream>>>(cnt, N, bsum);
    scan2_k<<<1, 64, 0, stream>>>(bsum, nb, rowptr, N, E);
    scan3_k<<<nb, 1024, 0, stream>>>(cnt, N, bsum, rowptr, nxt);
    scatter_k<<<ebl, 256, 0, stream>>>(src, dst, E, nxt, ssrc);

    const int AGG_BLOCKS = 2048;  // multiple of 8; slice = blockIdx & 7
    const int GEMM_BLOCKS = 512;

    mgemm_k<0><<<GEMM_BLOCKS, 256, 0, stream>>>(x, nullptr, Wp, h, nullptr, N);
    aggs_k<0><<<AGG_BLOCKS, 256, 0, stream>>>(h, rowptr, ssrc, (unsigned*)h2, nullptr, stats, N);
    bnfin_k<<<1, 128, 0, stream>>>(stats, gammas, betas, ss, N);
    mgemm_k<1><<<GEMM_BLOCKS, 256, 0, stream>>>(nullptr, h2, Wp + 2048, h, ss, N);
    aggs_k<0><<<AGG_BLOCKS, 256, 0, stream>>>(h, rowptr, ssrc, (unsigned*)h2, nullptr, stats + 256, N);
    bnfin_k<<<1, 128, 0, stream>>>(stats + 256, gammas + 128, betas + 128, ss + 256, N);
    mgemm_k<1><<<GEMM_BLOCKS, 256, 0, stream>>>(nullptr, h2, Wp + 4096, h, ss + 256, N);
    aggs_k<1><<<AGG_BLOCKS, 256, 0, stream>>>(h, rowptr, ssrc, nullptr, out, nullptr, N);
    lsm_k<<<1024, 256, 0, stream>>>(out, N);
}

// Round 9
// 647.486 us; speedup vs baseline: 1.2782x; 1.2782x over previous
//
#include <hip/hip_runtime.h>

#define BN_EPS 1e-5f

typedef __attribute__((ext_vector_type(8))) short bf16x8;
typedef __attribute__((ext_vector_type(4))) float f32x4;

union VU {
    uint4 u;
    bf16x8 b;
};

// ---------------- CSR build ----------------

__global__ __launch_bounds__(256) void count_k(const int* __restrict__ dst, int E, int* __restrict__ cnt) {
    int i = blockIdx.x * 256 + threadIdx.x;
    if (i < E) atomicAdd(&cnt[dst[i]], 1);
}

__global__ __launch_bounds__(1024) void scan1_k(const int* __restrict__ cnt, int n, int* __restrict__ bsum) {
    __shared__ int sh[1024];
    int i = blockIdx.x * 1024 + threadIdx.x;
    sh[threadIdx.x] = (i < n) ? cnt[i] : 0;
    __syncthreads();
    for (int s = 512; s > 0; s >>= 1) {
        if (threadIdx.x < (unsigned)s) sh[threadIdx.x] += sh[threadIdx.x + s];
        __syncthreads();
    }
    if (threadIdx.x == 0) bsum[blockIdx.x] = sh[0];
}

__global__ void scan2_k(int* bsum, int nb, int* rowptr, int n, int E) {
    if (threadIdx.x == 0 && blockIdx.x == 0) {
        int run = 0;
        for (int i = 0; i < nb; ++i) { int v = bsum[i]; bsum[i] = run; run += v; }
        rowptr[n] = E;
    }
}

__global__ __launch_bounds__(1024) void scan3_k(const int* __restrict__ cnt, int n, const int* __restrict__ boff,
                                                int* __restrict__ rowptr, int* __restrict__ nxt) {
    __shared__ int sh[1024];
    int i = blockIdx.x * 1024 + threadIdx.x;
    int v = (i < n) ? cnt[i] : 0;
    sh[threadIdx.x] = v;
    __syncthreads();
    for (int s = 1; s < 1024; s <<= 1) {
        int t = (threadIdx.x >= (unsigned)s) ? sh[threadIdx.x - s] : 0;
        __syncthreads();
        sh[threadIdx.x] += t;
        __syncthreads();
    }
    if (i < n) {
        int ex = boff[blockIdx.x] + sh[threadIdx.x] - v;
        rowptr[i] = ex;
        nxt[i] = ex;
    }
}

__global__ __launch_bounds__(256) void scatter_k(const int* __restrict__ src, const int* __restrict__ dst, int E,
                                                 int* __restrict__ nxt, int* __restrict__ ssrc) {
    int i = blockIdx.x * 256 + threadIdx.x;
    if (i < E) {
        int d = dst[i];
        int p = atomicAdd(&nxt[d], 1);
        ssrc[p] = src[i];
    }
}

// ---------------- helpers ----------------

static __device__ __forceinline__ unsigned short f2bf(float f) {
    unsigned u = __float_as_uint(f);
    unsigned r = (u + 0x7FFFu + ((u >> 16) & 1u)) >> 16;  // RNE
    return (unsigned short)r;
}
static __device__ __forceinline__ float bf_lo(unsigned u) { return __uint_as_float(u << 16); }
static __device__ __forceinline__ float bf_hi(unsigned u) { return __uint_as_float(u & 0xFFFF0000u); }

// ---------------- prep: pack W (3 layers f32 128x128) into bf16 MFMA fragments ----------------

__global__ __launch_bounds__(256) void prepw_k(const float* __restrict__ Ws, uint4* __restrict__ Wp) {
    int id = blockIdx.x * 256 + threadIdx.x;
    if (id >= 3 * 4 * 8 * 64) return;
    int lane = id & 63;
    int nt = (id >> 6) & 7;
    int kt = (id >> 9) & 3;
    int L = id >> 11;
    int quad = lane >> 4, l16 = lane & 15;
    const float* wsrc = Ws + L * 16384 + (kt * 32 + quad * 8) * 128 + nt * 16 + l16;
    unsigned short s[8];
#pragma unroll
    for (int j = 0; j < 8; ++j) s[j] = f2bf(wsrc[j * 128]);
    uint4 pk;
    pk.x = (unsigned)s[0] | ((unsigned)s[1] << 16);
    pk.y = (unsigned)s[2] | ((unsigned)s[3] << 16);
    pk.z = (unsigned)s[4] | ((unsigned)s[5] << 16);
    pk.w = (unsigned)s[6] | ((unsigned)s[7] << 16);
    Wp[id] = pk;
}

// ---------------- MFMA GEMM: H(bf16, SLICE-MAJOR) = f(X) @ Wp ----------------
// Slice-major: H is 8 arrays of N x 16 feats (32B rows); slice s at H + s*N*16, holds feats [16s,16s+16).
// MODE 0: X = f32 row-major (cvt fused).  MODE 1: X = bf16 slice-major, f = BN+ReLU (fused).

template <int MODE>
__global__ __launch_bounds__(256) void mgemm_k(const float* __restrict__ Xf, const unsigned short* __restrict__ Xb,
                                               const uint4* __restrict__ Wp, unsigned short* __restrict__ H,
                                               const float* __restrict__ ss, int n) {
    int lane = threadIdx.x & 63;
    int quad = lane >> 4, l16 = lane & 15;
    int wid = (blockIdx.x * 256 + threadIdx.x) >> 6;
    int nw = (gridDim.x * 256) >> 6;
    int ntiles = (n + 15) >> 4;

    VU b[4][8];
#pragma unroll
    for (int kt = 0; kt < 4; ++kt)
#pragma unroll
        for (int nt = 0; nt < 8; ++nt) b[kt][nt].u = Wp[(kt * 8 + nt) * 64 + lane];

    auto loadA = [&](int tile, VU* a) {
        int row = tile * 16 + l16;
#pragma unroll
        for (int kt = 0; kt < 4; ++kt) {
            float f[8];
            if (MODE == 0) {
                const float* xr = Xf + (size_t)row * 128 + kt * 32 + quad * 8;
                float4 u0 = *(const float4*)(xr);
                float4 u1 = *(const float4*)(xr + 4);
                f[0] = u0.x; f[1] = u0.y; f[2] = u0.z; f[3] = u0.w;
                f[4] = u1.x; f[5] = u1.y; f[6] = u1.z; f[7] = u1.w;
            } else {
                int sl = kt * 2 + (quad >> 1);
                uint4 u = *(const uint4*)(Xb + ((size_t)sl * n + row) * 16 + (quad & 1) * 8);
                f[0] = bf_lo(u.x); f[1] = bf_hi(u.x); f[2] = bf_lo(u.y); f[3] = bf_hi(u.y);
                f[4] = bf_lo(u.z); f[5] = bf_hi(u.z); f[6] = bf_lo(u.w); f[7] = bf_hi(u.w);
                const float4* scp = (const float4*)(ss + kt * 32 + quad * 8);
                const float4* shp = (const float4*)(ss + 128 + kt * 32 + quad * 8);
                float4 c0 = scp[0], c1 = scp[1], d0 = shp[0], d1 = shp[1];
                f[0] = fmaxf(fmaf(f[0], c0.x, d0.x), 0.f);
                f[1] = fmaxf(fmaf(f[1], c0.y, d0.y), 0.f);
                f[2] = fmaxf(fmaf(f[2], c0.z, d0.z), 0.f);
                f[3] = fmaxf(fmaf(f[3], c0.w, d0.w), 0.f);
                f[4] = fmaxf(fmaf(f[4], c1.x, d1.x), 0.f);
                f[5] = fmaxf(fmaf(f[5], c1.y, d1.y), 0.f);
                f[6] = fmaxf(fmaf(f[6], c1.z, d1.z), 0.f);
                f[7] = fmaxf(fmaf(f[7], c1.w, d1.w), 0.f);
            }
            uint4 pk;
            pk.x = (unsigned)f2bf(f[0]) | ((unsigned)f2bf(f[1]) << 16);
            pk.y = (unsigned)f2bf(f[2]) | ((unsigned)f2bf(f[3]) << 16);
            pk.z = (unsigned)f2bf(f[4]) | ((unsigned)f2bf(f[5]) << 16);
            pk.w = (unsigned)f2bf(f[6]) | ((unsigned)f2bf(f[7]) << 16);
            a[kt].u = pk;
        }
    };

    int t = wid;
    VU a[4];
    if (t < ntiles) loadA(t, a);

    while (t < ntiles) {
        int tn = t + nw;
        VU an[4];
        if (tn < ntiles) loadA(tn, an);

        f32x4 acc[8];
#pragma unroll
        for (int nt = 0; nt < 8; ++nt) acc[nt] = (f32x4){0.f, 0.f, 0.f, 0.f};
#pragma unroll
        for (int kt = 0; kt < 4; ++kt)
#pragma unroll
            for (int nt = 0; nt < 8; ++nt)
                acc[nt] = __builtin_amdgcn_mfma_f32_16x16x32_bf16(b[kt][nt].b, a[kt].b, acc[nt], 0, 0, 0);

        int row = t * 16 + l16;
#pragma unroll
        for (int nt = 0; nt < 8; ++nt) {
            uint2 pk;
            pk.x = (unsigned)f2bf(acc[nt][0]) | ((unsigned)f2bf(acc[nt][1]) << 16);
            pk.y = (unsigned)f2bf(acc[nt][2]) | ((unsigned)f2bf(acc[nt][3]) << 16);
            *(uint2*)(H + ((size_t)nt * n + row) * 16 + quad * 4) = pk;
        }

#pragma unroll
        for (int kt = 0; kt < 4; ++kt) a[kt] = an[kt];
        t = tn;
    }
}

// ---------------- Sliced aggregation, 8 nodes per wave ----------------
// slice = blockIdx & 7 (XCD-pinned, L2-resident 3.2 MB slice).
// Lane = (g, f): 8-lane group g owns node base+g; lane f accumulates feats (2f,2f+1) over ALL its
// node's edges -> no cross-lane reduction. Batches of 8 clamped branch-free edge-slots:
// 8 idx + 8 gathers in flight covering 64 edges/wave-batch.

template <int MODE>
__global__ __launch_bounds__(256) void aggs_k(const unsigned short* __restrict__ H, const int* __restrict__ rowptr,
                                              const int* __restrict__ ssrc, unsigned* __restrict__ outb,
                                              float* __restrict__ outf, float* __restrict__ stats, int n) {
    __shared__ float sred[4][4][8];
    int slice = blockIdx.x & 7;
    int bg = blockIdx.x >> 3;
    int lane = threadIdx.x & 63;
    int wv = threadIdx.x >> 6;
    int g = lane >> 3;  // node group
    int f = lane & 7;   // feature pair: feats 2f, 2f+1 of this slice
    int wid = bg * 4 + wv;
    int nwave = (gridDim.x >> 3) * 4;
    const unsigned short* hs = H + (size_t)slice * n * 16 + f * 2;
    float s0 = 0, s1 = 0, q0 = 0, q1 = 0;

    for (int base = wid * 8; base < n; base += nwave * 8) {
        int node = base + g;
        bool valid = node < n;
        int cn = valid ? node : (n - 1);
        int beg = rowptr[cn];
        int end = valid ? rowptr[cn + 1] : beg;
        float ax = 0.f, ay = 0.f;

        for (int s = 0;; s += 8) {
            if (__ballot((beg + s) < end) == 0) break;
            int idx[8];
            float sc[8];
#pragma unroll
            for (int k = 0; k < 8; ++k) {
                int j = beg + s + k;
                int cj = j < end ? j : end - 1;
                cj = cj < 0 ? 0 : cj;
                idx[k] = ssrc[cj];
                sc[k] = (j < end) ? 1.f : 0.f;
            }
            unsigned v[8];
#pragma unroll
            for (int k = 0; k < 8; ++k) v[k] = *(const unsigned*)(hs + (size_t)idx[k] * 16);
#pragma unroll
            for (int k = 0; k < 8; ++k) {
                ax = fmaf(sc[k], bf_lo(v[k]), ax);
                ay = fmaf(sc[k], bf_hi(v[k]), ay);
            }
        }

        if (MODE == 0) {
            if (valid) outb[((size_t)slice * n + node) * 8 + f] = (unsigned)f2bf(ax) | ((unsigned)f2bf(ay) << 16);
            s0 += ax; q0 += ax * ax;
            s1 += ay; q1 += ay * ay;
        } else {
            if (valid) *(float2*)(outf + (size_t)node * 128 + slice * 16 + f * 2) = make_float2(ax, ay);
        }
    }

    if (MODE == 0) {
        // combine the 8 node-groups (lane bits 3,4,5), then cross-wave via LDS
        s0 += __shfl_xor(s0, 8); s0 += __shfl_xor(s0, 16); s0 += __shfl_xor(s0, 32);
        s1 += __shfl_xor(s1, 8); s1 += __shfl_xor(s1, 16); s1 += __shfl_xor(s1, 32);
        q0 += __shfl_xor(q0, 8); q0 += __shfl_xor(q0, 16); q0 += __shfl_xor(q0, 32);
        q1 += __shfl_xor(q1, 8); q1 += __shfl_xor(q1, 16); q1 += __shfl_xor(q1, 32);
        if (g == 0) {
            sred[wv][0][f] = s0;
            sred[wv][1][f] = s1;
            sred[wv][2][f] = q0;
            sred[wv][3][f] = q1;
        }
        __syncthreads();
        if (wv == 0 && g == 0) {
            float t0 = (sred[0][0][f] + sred[1][0][f]) + (sred[2][0][f] + sred[3][0][f]);
            float t1 = (sred[0][1][f] + sred[1][1][f]) + (sred[2][1][f] + sred[3][1][f]);
            float t2 = (sred[0][2][f] + sred[1][2][f]) + (sred[2][2][f] + sred[3][2][f]);
            float t3 = (sred[0][3][f] + sred[1][3][f]) + (sred[2][3][f] + sred[3][3][f]);
            atomicAdd(&stats[slice * 16 + 2 * f], t0);
            atomicAdd(&stats[slice * 16 + 2 * f + 1], t1);
            atomicAdd(&stats[128 + slice * 16 + 2 * f], t2);
            atomicAdd(&stats[128 + slice * 16 + 2 * f + 1], t3);
        }
    }
}

// ---------------- log_softmax in-place over out [n][128] ----------------

__global__ __launch_bounds__(256) void lsm_k(float* __restrict__ out, int n) {
    int lane = threadIdx.x & 63;
    int wid = (blockIdx.x * 256 + threadIdx.x) >> 6;
    int nw = (gridDim.x * 256) >> 6;
    for (int node = wid; node < n; node += nw) {
        float2 v = *(float2*)(out + (size_t)node * 128 + 2 * lane);
        float m = fmaxf(v.x, v.y);
#pragma unroll
        for (int off = 32; off > 0; off >>= 1) m = fmaxf(m, __shfl_xor(m, off));
        float ex = expf(v.x - m) + expf(v.y - m);
#pragma unroll
        for (int off = 32; off > 0; off >>= 1) ex += __shfl_xor(ex, off);
        float lse = m + logf(ex);
        *(float2*)(out + (size_t)node * 128 + 2 * lane) = make_float2(v.x - lse, v.y - lse);
    }
}

// ---------------- BN finalize ----------------

__global__ void bnfin_k(const float* __restrict__ stats, const float* __restrict__ gamma,
                        const float* __restrict__ beta, float* __restrict__ ss, int n) {
    int f = threadIdx.x;
    if (f < 128) {
        float mu = stats[f] / n;
        float var = stats[128 + f] / n - mu * mu;
        float rs = rsqrtf(fmaxf(var, 0.f) + BN_EPS);
        float sc = gamma[f] * rs;
        ss[f] = sc;
        ss[128 + f] = beta[f] - mu * sc;
    }
}

// ---------------- driver ----------------

extern "C" void kernel_launch(void* const* d_in, const int* in_sizes, int n_in,
                              void* d_out, int out_size, void* d_ws, size_t ws_size,
                              hipStream_t stream) {
    const float* x = (const float*)d_in[0];
    const int* ei = (const int*)d_in[1];
    const float* Ws = (const float*)d_in[2];
    const float* gammas = (const float*)d_in[3];
    const float* betas = (const float*)d_in[4];
    int N = in_sizes[0] / 128;
    int E = in_sizes[1] / 2;
    const int* src = ei;
    const int* dst = ei + E;
    float* out = (float*)d_out;

    char* w = (char*)d_ws;
    size_t o = 0;
    auto alloc = [&](size_t bytes) { char* p = w + o; o += (bytes + 511) & ~511ull; return p; };
    unsigned short* h = (unsigned short*)alloc((size_t)N * 128 * 2);   // bf16 slice-major GEMM out / agg in
    unsigned short* h2 = (unsigned short*)alloc((size_t)N * 128 * 2);  // bf16 slice-major agg out / GEMM in
    int* cnt = (int*)alloc((size_t)N * 4);
    int* rowptr = (int*)alloc(((size_t)N + 1) * 4);
    int* nxt = (int*)alloc((size_t)N * 4);
    int* bsum = (int*)alloc(4096);
    int* ssrc = (int*)alloc((size_t)E * 4);
    uint4* Wp = (uint4*)alloc(3 * 2048 * 16);
    float* stats = (float*)alloc(512 * 4);
    float* ss = (float*)alloc(512 * 4);

    hipMemsetAsync(cnt, 0, (size_t)N * 4, stream);
    hipMemsetAsync(stats, 0, 512 * 4, stream);

    int ebl = (E + 255) / 256;
    int nb = (N + 1023) / 1024;
    prepw_k<<<24, 256, 0, stream>>>(Ws, Wp);
    count_k<<<ebl, 256, 0, stream>>>(dst, E, cnt);
    scan1_k<<<nb, 1024, 0, stream>>>(cnt, N, bsum);
    scan2_k<<<1, 64, 0, stream>>>(bsum, nb, rowptr, N, E);
    scan3_k<<<nb, 1024, 0, stream>>>(cnt, N, bsum, rowptr, nxt);
    scatter_k<<<ebl, 256, 0, stream>>>(src, dst, E, nxt, ssrc);

    const int AGG_BLOCKS = 2048;  // multiple of 8; slice = blockIdx & 7
    const int GEMM_BLOCKS = 512;

    mgemm_k<0><<<GEMM_BLOCKS, 256, 0, stream>>>(x, nullptr, Wp, h, nullptr, N);
    aggs_k<0><<<AGG_BLOCKS, 256, 0, stream>>>(h, rowptr, ssrc, (unsigned*)h2, nullptr, stats, N);
    bnfin_k<<<1, 128, 0, stream>>>(stats, gammas, betas, ss, N);
    mgemm_k<1><<<GEMM_BLOCKS, 256, 0, stream>>>(nullptr, h2, Wp + 2048, h, ss, N);
    aggs_k<0><<<AGG_BLOCKS, 256, 0, stream>>>(h, rowptr, ssrc, (unsigned*)h2, nullptr, stats + 256, N);
    bnfin_k<<<1, 128, 0, stream>>>(stats + 256, gammas + 128, betas + 128, ss + 256, N);
    mgemm_k<1><<<GEMM_BLOCKS, 256, 0, stream>>>(nullptr, h2, Wp + 4096, h, ss + 256, N);
    aggs_k<1><<<AGG_BLOCKS, 256, 0, stream>>>(h, rowptr, ssrc, nullptr, out, nullptr, N);
    lsm_k<<<1024, 256, 0, stream>>>(out, N);
}